// Round 9
// baseline (350.660 us; speedup 1.0000x reference)
//
#include <hip/hip_runtime.h>
#include <math.h>

#define FC 256
#define NB 8
#define RS 136   // LDS act row stride in fp16 elems (128 ci + 8 pad)

typedef __attribute__((ext_vector_type(8))) _Float16 f16x8;
typedef __attribute__((ext_vector_type(4))) float f32x4;

typedef const unsigned int __attribute__((address_space(1))) GASU;
typedef unsigned int __attribute__((address_space(3))) LASU;

__device__ __forceinline__ float lrelu(float v) { return v > 0.f ? v : 0.2f * v; }
__device__ __forceinline__ unsigned short f2h(float f) {
  _Float16 h = (_Float16)f;
  return *(unsigned short*)&h;
}
// raw barrier + manual waitcnt (avoid __syncthreads' full vmcnt(0) drain)
__device__ __forceinline__ void bar() { asm volatile("s_barrier" ::: "memory"); }
__device__ __forceinline__ void wait_lgkm0() { asm volatile("s_waitcnt lgkmcnt(0)" ::: "memory"); }
// Pre-barrier wait: vmcnt(N) keeps the DMA prefetch chain in flight, lgkmcnt(0)
// guarantees this wave's ds_reads of the to-be-overwritten buffer retired before
// it passes the barrier (R6 race).
template<int N> __device__ __forceinline__ void wait_vm_lgkm() {
  asm volatile("s_waitcnt vmcnt(%0) lgkmcnt(0)" :: "n"(N) : "memory");
}

// ---------------- weight pack: fp32 -> fp16 ----------------
#define N1 344064   // 3*7*128*128   enc w123  [l][kw][cout][cin]
#define N2 196608   // 4*3*128*128   enc w4567 [l][kw][cout][cin]
#define N3 32768    // 256*128       enc w8    [cout][cin]
#define NTOT 573440
#define NWN 2097152 // 8*512*512     wnet      [l][row=2ch+mat][k=kw*256+ci]
#define NCNT 128    // split-K completion counters (zeroed here every call)

__global__ void pack_kernel(const float* __restrict__ w123,
                            const float* __restrict__ w4567,
                            const float* __restrict__ w8,
                            const float* __restrict__ mw,
                            const float* __restrict__ gw,
                            unsigned short* __restrict__ wp,
                            unsigned short* __restrict__ wn,
                            int* __restrict__ cnt) {
  int idx = blockIdx.x * 512 + threadIdx.x;
  if (idx < N1) {
    int ci = idx & 127, co = (idx >> 7) & 127, t = idx >> 14;  // t = l*7+kw
    int l = t / 7, kw = t % 7;
    wp[idx] = f2h(w123[(((l * 128 + co) * 128) + ci) * 7 + kw]);
  } else if (idx < N1 + N2) {
    int k = idx - N1;
    int ci = k & 127, co = (k >> 7) & 127, t = k >> 14;        // t = l*3+kw
    int l = t / 3, kw = t % 3;
    wp[idx] = f2h(w4567[(((l * 128 + co) * 128) + ci) * 3 + kw]);
  } else if (idx < NTOT) {
    wp[idx] = f2h(w8[idx - N1 - N2]);
  } else if (idx < NTOT + NWN) {
    int k2 = idx - NTOT;
    int li = k2 >> 18, r = (k2 >> 9) & 511, k = k2 & 511;
    int ch = r >> 1, mat = r & 1, kw = k >> 8, ci = k & 255;
    const float* src = mat ? gw : mw;
    wn[k2] = f2h(src[(((size_t)li * 256 + ch) * 256 + ci) * 2 + kw]);
  } else if (idx < NTOT + NWN + NCNT) {
    cnt[idx - NTOT - NWN] = 0;
  }
}

// ---- async stage of one (kw, ci32) weight chunk (128 cout x 32 ci fp16 = 8KB) ----
// LDS element (r, c8) lives at r*64B + ((c8 + (r>>2))&3)*16B -> 2-way-free ds_read_b128.
__device__ __forceinline__ void stage_chunk(const unsigned short* __restrict__ wp,
                                            int kw, int ks,
                                            unsigned short* __restrict__ dst, int tid) {
  const int r = tid >> 2;
  const int c8 = ((tid & 3) - (tid >> 4)) & 3;
  const unsigned short* g = wp + ((kw << 7) + r) * 128 + ks * 32 + c8 * 8;
  __builtin_amdgcn_global_load_lds((GASU*)g, (LASU*)(dst + ((tid >> 6) << 9)), 16, 0, 0);
}

// ---------------- staged MFMA conv layer, triple-buffered, raw barriers (R7) ----------------
// Per k-step s: wait vmcnt(1)+lgkmcnt(0) -> s_barrier -> issue chunk s+2 into B[(s+2)%3]
// -> ds_read A/B -> MFMA.
template<int KW, int POFF, int PIN, int POUT, int MC, int MN, int OM>
__device__ __forceinline__ void mlayer_s(const unsigned short* __restrict__ wp,
                                         const unsigned short* __restrict__ sin_,
                                         unsigned short* __restrict__ sout,
                                         unsigned short* __restrict__ gact,
                                         unsigned short* __restrict__ wbuf,
                                         int tid, int frame) {
  constexpr int HRIN = PIN / 2 + 4;
  constexpr int HROUT = POUT / 2 + 4;
  constexpr int Nt = (POUT + 15) / 16;
  constexpr int MNg = Nt / MN;          // MCg*MNg == 8 (one macro-tile per wave)
  constexpr int NS = KW * 4;

  const int wid = tid >> 6, lane = tid & 63, nl = lane & 15, q = lane >> 4;
  const int mcg = wid / MNg, mng = wid % MNg;
  const int ct0 = mcg * MC, nt0 = mng * MN;

  int jj[MN]; bool val[MN]; int rofs[MN][KW];
#pragma unroll
  for (int jn = 0; jn < MN; ++jn) {
    int n = (nt0 + jn) * 16 + nl;
    val[jn] = (n < POUT);
    jj[jn] = val[jn] ? n : 0;
#pragma unroll
    for (int kw = 0; kw < KW; ++kw) {
      int P = 2 * jj[jn] + kw - POFF + 4;
      rofs[jn][kw] = ((P & 1) * HRIN + (P >> 1)) * RS + q * 8;
    }
  }
  int aofs[MC];
#pragma unroll
  for (int i = 0; i < MC; ++i) {
    int r = (ct0 + i) * 16 + nl;
    aofs[i] = r * 32 + ((q + (r >> 2)) & 3) * 8;
  }

  f32x4 acc[MC][MN];
#pragma unroll
  for (int i = 0; i < MC; ++i)
#pragma unroll
    for (int jn = 0; jn < MN; ++jn) acc[i][jn] = (f32x4){0.f, 0.f, 0.f, 0.f};

  // prologue: issue chunks 0 and 1
  stage_chunk(wp, 0, 0, wbuf, tid);
  stage_chunk(wp, 0, 1, wbuf + 4096, tid);

#pragma unroll
  for (int s = 0; s < NS; ++s) {
    if (s < NS - 1) wait_vm_lgkm<1>(); else wait_vm_lgkm<0>();
    bar();
    if (s + 2 < NS)
      stage_chunk(wp, (s + 2) >> 2, (s + 2) & 3, wbuf + ((s + 2) % 3) * 4096, tid);
    const unsigned short* cb = wbuf + (s % 3) * 4096;
    const int kw = s >> 2, ks = s & 3;
    f16x8 a[MC], b[MN];
#pragma unroll
    for (int i = 0; i < MC; ++i) a[i] = *(const f16x8*)(cb + aofs[i]);
#pragma unroll
    for (int jn = 0; jn < MN; ++jn) b[jn] = *(const f16x8*)(sin_ + rofs[jn][kw] + ks * 32);
#pragma unroll
    for (int i = 0; i < MC; ++i)
#pragma unroll
      for (int jn = 0; jn < MN; ++jn)
        acc[i][jn] = __builtin_amdgcn_mfma_f32_16x16x32_f16(a[i], b[jn], acc[i][jn], 0, 0, 0);
  }

  // epilogue: C tile: col n = nl, rows cout = ct*16 + q*4 + r
#pragma unroll
  for (int i = 0; i < MC; ++i) {
#pragma unroll
    for (int jn = 0; jn < MN; ++jn) {
      if (!val[jn]) continue;
      unsigned int lo = (unsigned)f2h(lrelu(acc[i][jn][0])) | ((unsigned)f2h(lrelu(acc[i][jn][1])) << 16);
      unsigned int hi = (unsigned)f2h(lrelu(acc[i][jn][2])) | ((unsigned)f2h(lrelu(acc[i][jn][3])) << 16);
      const int j = jj[jn];
      if (OM == 1) {
        *(uint2*)(gact + ((size_t)frame * POUT + j) * 128 + (ct0 + i) * 16 + q * 4) = make_uint2(lo, hi);
      } else {
        const int row = (j & 1) * HROUT + (j >> 1) + 2;
        *(uint2*)(sout + (size_t)row * RS + (ct0 + i) * 16 + q * 4) = make_uint2(lo, hi);
      }
    }
  }
  if (OM == 0) {
    constexpr int DEND = ((POUT - 1) >> 1) + 3;
    constexpr int NZ = 2 + (HROUT - DEND);
    unsigned int* zp = (unsigned int*)sout;
    for (int s2 = tid; s2 < 2 * NZ * 68; s2 += 512) {
      int col = s2 % 68, rr = s2 / 68;
      int par = rr / NZ, rz = rr % NZ;
      int row = rz < 2 ? rz : DEND + rz - 2;
      zp[((size_t)par * HROUT + row) * 68 + col] = 0;
    }
  }
  // layer boundary: LDS writes visible to all waves; no DMA outstanding
  wait_lgkm0();
  bar();
}

// ---------------- E1: L0..L4, one block per frame (staged weights, R7) ----------------
__global__ __launch_bounds__(512)
void encoder1(const float* __restrict__ x, const float* __restrict__ w0,
              const unsigned short* __restrict__ wp123,
              const unsigned short* __restrict__ wp4,
              unsigned short* __restrict__ act4g) {
  __shared__ __align__(16) unsigned short actA[18496];  // act0 (2*68 rows); later act2(2*20)+act3(2*12)
  __shared__ __align__(16) unsigned short actB[9792];   // act1 (2*36 rows); s_x overlaid pre-L1
  __shared__ __align__(16) unsigned short wbuf[12288];  // 3 x 8KB weight chunk buffers
  float* s_x = (float*)actB;                            // 262 floats, dead before L1 epilogue
  const int tid = threadIdx.x;
  const int frame = blockIdx.x;
  const int bb = frame >> 8;
  const int t = (frame & 255) + 256;

  if (tid < 256) s_x[3 + tid] = x[((bb << 8) + tid) * 512 + t];
  else if (tid < 259) s_x[tid - 256] = 0.f;
  else if (tid < 262) s_x[tid] = 0.f;
  wait_lgkm0();
  bar();

  // L0: 1->128, k7 s2 p3 (fp32 VALU), store fp16 parity layout
  {
    const int c = tid & 127;
    const int half = tid >> 7;
    float wv[7];
#pragma unroll
    for (int k = 0; k < 7; ++k) wv[k] = w0[c * 7 + k];
    for (int j = half * 32; j < half * 32 + 32; ++j) {
      float s = 0.f;
#pragma unroll
      for (int k = 0; k < 7; ++k) s += wv[k] * s_x[2 * j + k];
      int row = ((j & 1) ? 68 : 0) + (j >> 1) + 2;
      actA[row * RS + c] = f2h(lrelu(s));
    }
    unsigned int* zp = (unsigned int*)actA;
    for (int s2 = tid; s2 < 2 * 4 * 68; s2 += 512) {
      int col = s2 % 68;
      int rr = s2 / 68;
      int par = rr >> 2, r2 = rr & 3;
      int row = (r2 < 2) ? r2 : (64 + r2);
      zp[((size_t)par * 68 + row) * 68 + col] = 0;
    }
  }
  wait_lgkm0();
  bar();

  mlayer_s<7, 3, 128, 64, 2, 2, 0>(wp123,          actA, actB, nullptr, wbuf, tid, frame);        // L1
  mlayer_s<7, 3, 64, 32, 2, 1, 0>(wp123 + 114688,  actB, actA, nullptr, wbuf, tid, frame);        // L2
  mlayer_s<7, 3, 32, 16, 1, 1, 0>(wp123 + 229376,  actA, actA + 5440, nullptr, wbuf, tid, frame); // L3
  mlayer_s<3, 1, 16, 8, 1, 1, 1>(wp4,              actA + 5440, nullptr, act4g, wbuf, tid, frame);// L4 -> global
}

// ---------------- generic MFMA conv layer (encoder2, unchanged) ----------------
template<int KW, int POFF, int PIN, int POUT, int FPB, int COUT, int MC, int MN, int OM, bool FLATIN>
__device__ __forceinline__ void mlayer(const unsigned short* __restrict__ wp,
                                       const unsigned short* __restrict__ sin_,
                                       unsigned short* __restrict__ sout,
                                       float* __restrict__ gout,
                                       int tid, int frame0) {
  constexpr int HRIN  = PIN / 2 + 4;
  constexpr int HROUT = POUT / 2 + 4;
  constexpr int NVAL = POUT * FPB;
  constexpr int Nt = (NVAL + 15) / 16;
  constexpr int Ct = COUT / 16;
  constexpr int MCg = Ct / MC, MNg = Nt / MN;
  constexpr int KS = 4;            // CIN=128 / 32
  constexpr int NS = KW * KS;
  constexpr int DA = NS < 6 ? NS : 6;
  constexpr int DB = NS < 3 ? NS : 3;
  constexpr int L2P = POUT == 1 ? 0 : POUT == 2 ? 1 : POUT == 4 ? 2 : POUT == 8 ? 3 :
                      POUT == 16 ? 4 : POUT == 32 ? 5 : 6;

  const int wid = tid >> 6, lane = tid & 63, nl = lane & 15, q = lane >> 4;

  for (int mac = wid; mac < MCg * MNg; mac += 8) {
    const int mcg = mac / MNg, mng = mac % MNg;
    const int ct0 = mcg * MC, nt0 = mng * MN;
    int jj[MN]; bool val[MN];
#pragma unroll
    for (int jn = 0; jn < MN; ++jn) {
      int n = (nt0 + jn) * 16 + nl;
      val[jn] = (n < NVAL);
      jj[jn] = val[jn] ? n : 0;
    }
    int rofs[MN][KW];
#pragma unroll
    for (int jn = 0; jn < MN; ++jn) {
      const int f = jj[jn] >> L2P, j = jj[jn] & (POUT - 1);
#pragma unroll
      for (int kw = 0; kw < KW; ++kw) {
        if (FLATIN) {
          rofs[jn][kw] = jj[jn] * RS + q * 8;
        } else {
          int P = 2 * j + kw - POFF + 4;
          rofs[jn][kw] = (f * 2 * HRIN + (P & 1) * HRIN + (P >> 1)) * RS + q * 8;
        }
      }
    }
    int abase[MC];
#pragma unroll
    for (int i = 0; i < MC; ++i) abase[i] = ((ct0 + i) * 16 + nl) * 128 + q * 8;

    f32x4 acc[MC][MN];
#pragma unroll
    for (int i = 0; i < MC; ++i)
#pragma unroll
      for (int jn = 0; jn < MN; ++jn) acc[i][jn] = (f32x4){0.f, 0.f, 0.f, 0.f};

    f16x8 A[DA][MC], B[DB][MN];
#pragma unroll
    for (int s = 0; s < DA; ++s) {
      const int kw = s / KS, ks = s % KS;
#pragma unroll
      for (int i = 0; i < MC; ++i)
        A[s][i] = *(const f16x8*)(wp + (size_t)kw * COUT * 128 + abase[i] + ks * 32);
    }
#pragma unroll
    for (int s = 0; s < DB; ++s) {
      const int kw = s / KS, ks = s % KS;
#pragma unroll
      for (int jn = 0; jn < MN; ++jn)
        B[s][jn] = *(const f16x8*)(sin_ + rofs[jn][kw] + ks * 32);
    }
#pragma unroll
    for (int s = 0; s < NS; ++s) {
      const int sa = s % DA, sb = s % DB;
#pragma unroll
      for (int i = 0; i < MC; ++i)
#pragma unroll
        for (int jn = 0; jn < MN; ++jn)
          acc[i][jn] = __builtin_amdgcn_mfma_f32_16x16x32_f16(A[sa][i], B[sb][jn], acc[i][jn], 0, 0, 0);
      if (s + DA < NS) {
        const int kw = (s + DA) / KS, ks = (s + DA) % KS;
#pragma unroll
        for (int i = 0; i < MC; ++i)
          A[sa][i] = *(const f16x8*)(wp + (size_t)kw * COUT * 128 + abase[i] + ks * 32);
      }
      if (s + DB < NS) {
        const int kw = (s + DB) / KS, ks = (s + DB) % KS;
#pragma unroll
        for (int jn = 0; jn < MN; ++jn)
          B[sb][jn] = *(const f16x8*)(sin_ + rofs[jn][kw] + ks * 32);
      }
    }
#pragma unroll
    for (int i = 0; i < MC; ++i) {
#pragma unroll
      for (int jn = 0; jn < MN; ++jn) {
        if (OM == 3) {
          if (val[jn]) {
            const int frame = frame0 + jj[jn];   // POUT==1
            float4 v = make_float4(acc[i][jn][0], acc[i][jn][1], acc[i][jn][2], acc[i][jn][3]);
            *(float4*)(gout + (size_t)frame * 256 + (ct0 + i) * 16 + q * 4) = v;
          }
        } else if (OM == 2) {
          if (val[jn]) {
            unsigned int lo = (unsigned)f2h(lrelu(acc[i][jn][0])) | ((unsigned)f2h(lrelu(acc[i][jn][1])) << 16);
            unsigned int hi = (unsigned)f2h(lrelu(acc[i][jn][2])) | ((unsigned)f2h(lrelu(acc[i][jn][3])) << 16);
            *(uint2*)(sout + (size_t)jj[jn] * RS + (ct0 + i) * 16 + q * 4) = make_uint2(lo, hi);
          }
        } else {
          if (val[jn]) {
            const int f = jj[jn] >> L2P, j = jj[jn] & (POUT - 1);
            const int row = f * 2 * HROUT + (j & 1) * HROUT + (j >> 1) + 2;
            unsigned int lo = (unsigned)f2h(lrelu(acc[i][jn][0])) | ((unsigned)f2h(lrelu(acc[i][jn][1])) << 16);
            unsigned int hi = (unsigned)f2h(lrelu(acc[i][jn][2])) | ((unsigned)f2h(lrelu(acc[i][jn][3])) << 16);
            *(uint2*)(sout + (size_t)row * RS + (ct0 + i) * 16 + q * 4) = make_uint2(lo, hi);
          }
        }
      }
    }
  }
  if (OM == 0) {
    constexpr int DEND = ((POUT - 1) >> 1) + 3;
    constexpr int NZ = 2 + (HROUT - DEND);
    constexpr int TOTU = FPB * 2 * NZ * (RS / 2);
    unsigned int* zp = (unsigned int*)sout;
    for (int s2 = tid; s2 < TOTU; s2 += 512) {
      int col = s2 % 68;
      int rr = s2 / 68;
      int fr = rr / (2 * NZ), r2 = rr % (2 * NZ);
      int par = r2 / NZ, rz = r2 % NZ;
      int row = rz < 2 ? rz : DEND + rz - 2;
      zp[((size_t)(fr * 2 + par) * HROUT + row) * 68 + col] = 0;
    }
    __syncthreads();
  } else if (OM == 2) {
    __syncthreads();
  }
}

// ---------------- E2: L5..L8, 8 frames per block (unchanged) ----------------
__global__ __launch_bounds__(512)
void encoder2(const unsigned short* __restrict__ act4g,
              const unsigned short* __restrict__ wp4,
              const unsigned short* __restrict__ wp8,
              float* __restrict__ h) {
  __shared__ __align__(16) unsigned short actP[17408];
  __shared__ __align__(16) unsigned short actQ[13056];
  __shared__ __align__(16) unsigned short actR[2176];
  const int tid = threadIdx.x;
  const int frame0 = blockIdx.x * 8;

  {
    uint4 z4 = make_uint4(0, 0, 0, 0);
    for (int s = tid; s < 2176; s += 512) ((uint4*)actP)[s] = z4;
    for (int s = tid; s < 1632; s += 512) ((uint4*)actQ)[s] = z4;
    for (int s = tid; s < 272; s += 512) ((uint4*)actR)[s] = z4;
  }
  __syncthreads();
  for (int c = tid; c < 1024; c += 512) {
    int f = c >> 7, rem = c & 127, pos = rem >> 4, o = (rem & 15) * 8;
    uint4 v = *(const uint4*)(act4g + ((size_t)(frame0 + f) * 8 + pos) * 128 + o);
    int P = pos + 4;
    int row = (P & 1) * 8 + (P >> 1);
    *(uint4*)(actP + ((size_t)f * 16 + row) * RS + o) = v;
  }
  __syncthreads();

  mlayer<3, 1, 8, 4, 8, 128, 2, 1, 0, false>(wp4 + 49152,  actP, actQ, nullptr, tid, frame0);  // L5
  mlayer<3, 1, 4, 2, 8, 128, 1, 1, 0, false>(wp4 + 98304,  actQ, actP, nullptr, tid, frame0);  // L6
  mlayer<3, 1, 2, 1, 8, 128, 1, 1, 2, false>(wp4 + 147456, actP, actR, nullptr, tid, frame0);  // L7 flat
  mlayer<1, 0, 1, 1, 8, 256, 1, 1, 3, true>(wp8,           actR, nullptr, h, tid, frame0);     // L8 -> h fp32
}

// ---------------- WaveNet fused layer (li 0..1), unchanged ----------------
__global__ __launch_bounds__(256)
void wnet_kernel(const unsigned short* __restrict__ wn,
                 const float* __restrict__ hsrc, float* __restrict__ hdst,
                 float* __restrict__ feats, int li, int init) {
  const int npos = 128 >> li, p = 1 << li, N = npos * 8, lnp = 7 - li;
  const int tid = threadIdx.x;
  const int nb = blockIdx.x >> 2, mb = blockIdx.x & 3;
  const int n0 = nb * 16;
  __shared__ __align__(16) unsigned short sB[16 * 520];

  for (int c = tid; c < 1024; c += 256) {
    const int nr = c >> 6, o = (c & 63) * 8;
    const int n = n0 + nr;
    unsigned short tmp[8] = {0, 0, 0, 0, 0, 0, 0, 0};
    if (n < N) {
      const int b = n >> lnp, kk = n & (npos - 1);
      const int t = 255 - (kk << (li + 1));
      const float* src = (o < 256) ? hsrc + ((size_t)(b * 256 + t - p)) * 256 + o
                                   : hsrc + ((size_t)(b * 256 + t)) * 256 + (o - 256);
#pragma unroll
      for (int e = 0; e < 8; ++e) tmp[e] = f2h(src[e]);
    }
    unsigned int u0 = (unsigned)tmp[0] | ((unsigned)tmp[1] << 16);
    unsigned int u1 = (unsigned)tmp[2] | ((unsigned)tmp[3] << 16);
    unsigned int u2 = (unsigned)tmp[4] | ((unsigned)tmp[5] << 16);
    unsigned int u3 = (unsigned)tmp[6] | ((unsigned)tmp[7] << 16);
    *(uint4*)(sB + (size_t)nr * 520 + o) = make_uint4(u0, u1, u2, u3);
  }
  __syncthreads();

  const int wid = tid >> 6, lane = tid & 63, nl = lane & 15, q = lane >> 4;
  f32x4 acc[2];
  acc[0] = (f32x4){0.f, 0.f, 0.f, 0.f};
  acc[1] = (f32x4){0.f, 0.f, 0.f, 0.f};
  int arow[2];
#pragma unroll
  for (int i = 0; i < 2; ++i) arow[i] = (mb * 128 + (wid * 2 + i) * 16 + nl) * 512 + q * 8;
  const int bofs = nl * 520 + q * 8;

  f16x8 A[4][2], Bv[2];
#pragma unroll
  for (int s = 0; s < 4; ++s)
#pragma unroll
    for (int i = 0; i < 2; ++i) A[s][i] = *(const f16x8*)(wn + arow[i] + s * 32);
#pragma unroll
  for (int s = 0; s < 2; ++s) Bv[s] = *(const f16x8*)(sB + bofs + s * 32);
#pragma unroll
  for (int s = 0; s < 16; ++s) {
    const int sa = s & 3, sb = s & 1;
    acc[0] = __builtin_amdgcn_mfma_f32_16x16x32_f16(A[sa][0], Bv[sb], acc[0], 0, 0, 0);
    acc[1] = __builtin_amdgcn_mfma_f32_16x16x32_f16(A[sa][1], Bv[sb], acc[1], 0, 0, 0);
    if (s + 4 < 16) {
#pragma unroll
      for (int i = 0; i < 2; ++i) A[sa][i] = *(const f16x8*)(wn + arow[i] + (s + 4) * 32);
    }
    if (s + 2 < 16) Bv[sb] = *(const f16x8*)(sB + bofs + (s + 2) * 32);
  }

  const int n = n0 + nl;
  if (n < N) {
    const int b = n >> lnp, kk = n & (npos - 1);
    const int t = 255 - (kk << (li + 1));
    const size_t rowoff = ((size_t)(b * 256 + t)) * 256;
#pragma unroll
    for (int i = 0; i < 2; ++i) {
      const int ch = mb * 64 + (wid * 2 + i) * 8 + q * 2;
      const float z0 = tanhf(acc[i][0]) * (1.f / (1.f + expf(-acc[i][1])));
      const float z1 = tanhf(acc[i][2]) * (1.f / (1.f + expf(-acc[i][3])));
      float2 hv = *(const float2*)(hsrc + rowoff + ch);
      *(float2*)(hdst + rowoff + ch) = make_float2(hv.x + z0, hv.y + z1);
      if (kk == 0) {
        float* fp = feats + b * 256 + ch;
        if (init) { fp[0] = z0; fp[1] = z1; }
        else { fp[0] += z0; fp[1] += z1; }
      }
    }
  }
}

// ---------------- WaveNet split-K MERGED kernel (li 2..7) ----------------
// partA (partial GEMM) + fence/atomic-counter + last-block combine & epilogue in ONE launch.
template<int KC>
__global__ __launch_bounds__(256)
void wnet_split(const unsigned short* __restrict__ wn,
                const float* __restrict__ hsrc, float* __restrict__ hdst,
                float* __restrict__ feats, float* __restrict__ pb,
                int* __restrict__ cnt, int li, int cbase) {
  const int npos = 128 >> li, p = 1 << li, N = npos * 8, lnp = 7 - li;
  const int NN = (N + 15) / 16;
  const int ksplit = 512 / KC;
  const int tid = threadIdx.x;
  int bid = blockIdx.x;
  const int mb = bid & 3; bid >>= 2;
  const int nb = bid % NN; const int ks = bid / NN;
  const int n0 = nb * 16;
  const int kc0 = ks * KC;
  constexpr int RSB = KC + 8;
  __shared__ __align__(16) unsigned short sB[16 * RSB];
  __shared__ int s_last;

  for (int c = tid; c < 2 * KC; c += 256) {
    const int nr = c / (KC / 8), oc = c % (KC / 8), o = oc * 8;
    const int kg = kc0 + o;
    const int n = n0 + nr;
    unsigned short tmp[8] = {0, 0, 0, 0, 0, 0, 0, 0};
    if (n < N) {
      const int b = n >> lnp, kk = n & (npos - 1);
      const int t = 255 - (kk << (li + 1));
      const float* src = (kg < 256) ? hsrc + ((size_t)(b * 256 + t - p)) * 256 + kg
                                    : hsrc + ((size_t)(b * 256 + t)) * 256 + (kg - 256);
#pragma unroll
      for (int e = 0; e < 8; ++e) tmp[e] = f2h(src[e]);
    }
    unsigned int u0 = (unsigned)tmp[0] | ((unsigned)tmp[1] << 16);
    unsigned int u1 = (unsigned)tmp[2] | ((unsigned)tmp[3] << 16);
    unsigned int u2 = (unsigned)tmp[4] | ((unsigned)tmp[5] << 16);
    unsigned int u3 = (unsigned)tmp[6] | ((unsigned)tmp[7] << 16);
    *(uint4*)(sB + (size_t)nr * RSB + o) = make_uint4(u0, u1, u2, u3);
  }
  __syncthreads();

  const int wid = tid >> 6, lane = tid & 63, nl = lane & 15, q = lane >> 4;
  f32x4 acc[2];
  acc[0] = (f32x4){0.f, 0.f, 0.f, 0.f};
  acc[1] = (f32x4){0.f, 0.f, 0.f, 0.f};
  int arow[2];
#pragma unroll
  for (int i = 0; i < 2; ++i) arow[i] = (mb * 128 + (wid * 2 + i) * 16 + nl) * 512 + kc0 + q * 8;
  const int bofs = nl * RSB + q * 8;

  constexpr int NS = KC / 32;
  constexpr int DA = NS < 4 ? NS : 4;
  constexpr int DB = NS < 2 ? NS : 2;
  f16x8 A[DA][2], Bv[DB];
#pragma unroll
  for (int s = 0; s < DA; ++s)
#pragma unroll
    for (int i = 0; i < 2; ++i) A[s][i] = *(const f16x8*)(wn + arow[i] + s * 32);
#pragma unroll
  for (int s = 0; s < DB; ++s) Bv[s] = *(const f16x8*)(sB + bofs + s * 32);
#pragma unroll
  for (int s = 0; s < NS; ++s) {
    const int sa = s % DA, sb = s % DB;
    acc[0] = __builtin_amdgcn_mfma_f32_16x16x32_f16(A[sa][0], Bv[sb], acc[0], 0, 0, 0);
    acc[1] = __builtin_amdgcn_mfma_f32_16x16x32_f16(A[sa][1], Bv[sb], acc[1], 0, 0, 0);
    if (s + DA < NS) {
#pragma unroll
      for (int i = 0; i < 2; ++i) A[sa][i] = *(const f16x8*)(wn + arow[i] + (s + DA) * 32);
    }
    if (s + DB < NS) Bv[sb] = *(const f16x8*)(sB + bofs + (s + DB) * 32);
  }
  {
    float* base = pb + ((size_t)((ks * NN + nb) * 4 + mb) * 256 + tid) * 8;
    *(f32x4*)(base) = acc[0];
    *(f32x4*)(base + 4) = acc[1];
  }

  // release partials, count completions; last block for (nb,mb) combines
  __threadfence();
  __syncthreads();
  if (tid == 0) {
    int old = atomicAdd(cnt + cbase + (nb * 4 + mb), 1);
    s_last = (old == ksplit - 1) ? 1 : 0;
  }
  __syncthreads();
  if (!s_last) return;
  __threadfence();   // acquire: other blocks' pb writes now visible

  float a8[8] = {0, 0, 0, 0, 0, 0, 0, 0};
  for (int k2 = 0; k2 < ksplit; ++k2) {
    const float* base = pb + ((size_t)((k2 * NN + nb) * 4 + mb) * 256 + tid) * 8;
    float4 v0 = *(const float4*)(base);
    float4 v1 = *(const float4*)(base + 4);
    a8[0] += v0.x; a8[1] += v0.y; a8[2] += v0.z; a8[3] += v0.w;
    a8[4] += v1.x; a8[5] += v1.y; a8[6] += v1.z; a8[7] += v1.w;
  }
  const int n = n0 + nl;
  if (n < N) {
    const int b = n >> lnp, kk = n & (npos - 1);
    const int t = 255 - (kk << (li + 1));
    const size_t rowoff = ((size_t)(b * 256 + t)) * 256;
#pragma unroll
    for (int i = 0; i < 2; ++i) {
      const int ch = mb * 64 + (wid * 2 + i) * 8 + q * 2;
      const float z0 = tanhf(a8[i * 4 + 0]) * (1.f / (1.f + expf(-a8[i * 4 + 1])));
      const float z1 = tanhf(a8[i * 4 + 2]) * (1.f / (1.f + expf(-a8[i * 4 + 3])));
      float2 hv = *(const float2*)(hsrc + rowoff + ch);
      *(float2*)(hdst + rowoff + ch) = make_float2(hv.x + z0, hv.y + z1);
      if (kk == 0) {
        float* fp = feats + b * 256 + ch;
        fp[0] += z0; fp[1] += z1;
      }
    }
  }
}

__global__ void finalize_kernel(const float* __restrict__ feats,
                                const float* __restrict__ jw,
                                float* __restrict__ out) {
  __shared__ float red[256];
  const int b = blockIdx.x;
  const int tid = threadIdx.x;
  const float v = feats[b * 256 + tid];
  out[b * 256 + tid] = v;
  red[tid] = v * jw[tid];
  __syncthreads();
  for (int s = 128; s > 0; s >>= 1) {
    if (tid < s) red[tid] += red[tid + s];
    __syncthreads();
  }
  if (tid == 0) out[NB * 256 + b] = red[0];
}

extern "C" void kernel_launch(void* const* d_in, const int* in_sizes, int n_in,
                              void* d_out, int out_size, void* d_ws, size_t ws_size,
                              hipStream_t stream) {
  const float* x     = (const float*)d_in[0];
  const float* w0    = (const float*)d_in[1];
  const float* w123  = (const float*)d_in[2];
  const float* w4567 = (const float*)d_in[3];
  const float* w8    = (const float*)d_in[4];
  const float* mw    = (const float*)d_in[5];
  const float* gw    = (const float*)d_in[6];
  const float* jw    = (const float*)d_in[7];
  float* out = (float*)d_out;

  float* ws = (float*)d_ws;
  unsigned short* act4g = (unsigned short*)ws;            // 2,097,152 fp16
  float* h0    = ws + 1048576;                            // 524,288 f
  float* h1    = ws + 1572864;                            // 524,288 f
  float* feats = ws + 2097152;                            // 2,048 f
  unsigned short* wp = (unsigned short*)(ws + 2099200);   // 573,440 fp16
  unsigned short* wn = (unsigned short*)(ws + 2385920);   // 2,097,152 fp16
  float* pb    = ws + 3434496;                            // 262,144 f
  int* cnt     = (int*)(ws + 3696640);                    // 128 ints

  pack_kernel<<<5217, 512, 0, stream>>>(w123, w4567, w8, mw, gw, wp, wn, cnt);
  encoder1<<<2048, 512, 0, stream>>>(x, w0, wp, wp + N1, act4g);
  encoder2<<<256, 512, 0, stream>>>(act4g, wp + N1, wp + N1 + N2, h0);

  float* hs = h0; float* hd = h1;
  // counter base offsets per layer: li2:0(64) li3:64(32) li4:96(16) li5:112(8) li6:120(4) li7:124(4)
  const int cbase[8] = {0, 0, 0, 64, 96, 112, 120, 124};
  for (int i = 0; i < 8; ++i) {
    const unsigned short* wl = wn + (size_t)i * 262144;
    const int N = (128 >> i) * 8;
    const int nN = (N + 15) / 16;
    if (i < 2) {
      wnet_kernel<<<4 * nN, 256, 0, stream>>>(wl, hs, hd, feats, i, i == 0 ? 1 : 0);
    } else {
      if (i == 2)      wnet_split<256><<<4 * nN * 2,  256, 0, stream>>>(wl, hs, hd, feats, pb, cnt, i, cbase[i]);
      else if (i == 3) wnet_split<128><<<4 * nN * 4,  256, 0, stream>>>(wl, hs, hd, feats, pb, cnt, i, cbase[i]);
      else if (i == 4) wnet_split<64> <<<4 * nN * 8,  256, 0, stream>>>(wl, hs, hd, feats, pb, cnt, i, cbase[i]);
      else             wnet_split<32> <<<4 * nN * 16, 256, 0, stream>>>(wl, hs, hd, feats, pb, cnt, i, cbase[i]);
    }
    float* tmp = hd; hd = hs; hs = tmp;
  }
  finalize_kernel<<<NB, 256, 0, stream>>>(feats, jw, out);
}

// Round 10
// 274.583 us; speedup vs baseline: 1.2771x; 1.2771x over previous
//
#include <hip/hip_runtime.h>
#include <math.h>

#define FC 256
#define NB 8
#define RS 136   // LDS act row stride in fp16 elems (128 ci + 8 pad)

typedef __attribute__((ext_vector_type(8))) _Float16 f16x8;
typedef __attribute__((ext_vector_type(4))) float f32x4;

typedef const unsigned int __attribute__((address_space(1))) GASU;
typedef unsigned int __attribute__((address_space(3))) LASU;

__device__ __forceinline__ float lrelu(float v) { return v > 0.f ? v : 0.2f * v; }
__device__ __forceinline__ unsigned short f2h(float f) {
  _Float16 h = (_Float16)f;
  return *(unsigned short*)&h;
}
// raw barrier + manual waitcnt (avoid __syncthreads' full vmcnt(0) drain)
__device__ __forceinline__ void bar() { asm volatile("s_barrier" ::: "memory"); }
__device__ __forceinline__ void wait_lgkm0() { asm volatile("s_waitcnt lgkmcnt(0)" ::: "memory"); }
// Pre-barrier wait: vmcnt(N) keeps the DMA prefetch chain in flight, lgkmcnt(0)
// guarantees this wave's ds_reads of the to-be-overwritten buffer retired before
// it passes the barrier (R6 race).
template<int N> __device__ __forceinline__ void wait_vm_lgkm() {
  asm volatile("s_waitcnt vmcnt(%0) lgkmcnt(0)" :: "n"(N) : "memory");
}

// ---------------- weight pack: fp32 -> fp16 ----------------
#define N1 344064   // 3*7*128*128   enc w123  [l][kw][cout][cin]
#define N2 196608   // 4*3*128*128   enc w4567 [l][kw][cout][cin]
#define N3 32768    // 256*128       enc w8    [cout][cin]
#define NTOT 573440
#define NWN 2097152 // 8*512*512     wnet      [l][row=2ch+mat][k=kw*256+ci]

__global__ void pack_kernel(const float* __restrict__ w123,
                            const float* __restrict__ w4567,
                            const float* __restrict__ w8,
                            const float* __restrict__ mw,
                            const float* __restrict__ gw,
                            unsigned short* __restrict__ wp,
                            unsigned short* __restrict__ wn) {
  int idx = blockIdx.x * 512 + threadIdx.x;
  if (idx < N1) {
    int ci = idx & 127, co = (idx >> 7) & 127, t = idx >> 14;  // t = l*7+kw
    int l = t / 7, kw = t % 7;
    wp[idx] = f2h(w123[(((l * 128 + co) * 128) + ci) * 7 + kw]);
  } else if (idx < N1 + N2) {
    int k = idx - N1;
    int ci = k & 127, co = (k >> 7) & 127, t = k >> 14;        // t = l*3+kw
    int l = t / 3, kw = t % 3;
    wp[idx] = f2h(w4567[(((l * 128 + co) * 128) + ci) * 3 + kw]);
  } else if (idx < NTOT) {
    wp[idx] = f2h(w8[idx - N1 - N2]);
  } else if (idx < NTOT + NWN) {
    int k2 = idx - NTOT;
    int li = k2 >> 18, r = (k2 >> 9) & 511, k = k2 & 511;
    int ch = r >> 1, mat = r & 1, kw = k >> 8, ci = k & 255;
    const float* src = mat ? gw : mw;
    wn[k2] = f2h(src[(((size_t)li * 256 + ch) * 256 + ci) * 2 + kw]);
  }
}

// ---- async stage of one (kw, ci32) weight chunk (128 cout x 32 ci fp16 = 8KB) ----
// LDS element (r, c8) lives at r*64B + ((c8 + (r>>2))&3)*16B -> 2-way-free ds_read_b128.
__device__ __forceinline__ void stage_chunk(const unsigned short* __restrict__ wp,
                                            int kw, int ks,
                                            unsigned short* __restrict__ dst, int tid) {
  const int r = tid >> 2;
  const int c8 = ((tid & 3) - (tid >> 4)) & 3;
  const unsigned short* g = wp + ((kw << 7) + r) * 128 + ks * 32 + c8 * 8;
  __builtin_amdgcn_global_load_lds((GASU*)g, (LASU*)(dst + ((tid >> 6) << 9)), 16, 0, 0);
}

// ---------------- staged MFMA conv layer, triple-buffered, raw barriers ----------------
// Per k-step s: wait vmcnt(1)+lgkmcnt(0) -> s_barrier -> issue chunk s+2 into B[(s+2)%3]
// -> ds_read A/B -> MFMA.
template<int KW, int POFF, int PIN, int POUT, int MC, int MN, int OM>
__device__ __forceinline__ void mlayer_s(const unsigned short* __restrict__ wp,
                                         const unsigned short* __restrict__ sin_,
                                         unsigned short* __restrict__ sout,
                                         unsigned short* __restrict__ gact,
                                         unsigned short* __restrict__ wbuf,
                                         int tid, int frame) {
  constexpr int HRIN = PIN / 2 + 4;
  constexpr int HROUT = POUT / 2 + 4;
  constexpr int Nt = (POUT + 15) / 16;
  constexpr int MNg = Nt / MN;          // MCg*MNg == 8 (one macro-tile per wave)
  constexpr int NS = KW * 4;

  const int wid = tid >> 6, lane = tid & 63, nl = lane & 15, q = lane >> 4;
  const int mcg = wid / MNg, mng = wid % MNg;
  const int ct0 = mcg * MC, nt0 = mng * MN;

  int jj[MN]; bool val[MN]; int rofs[MN][KW];
#pragma unroll
  for (int jn = 0; jn < MN; ++jn) {
    int n = (nt0 + jn) * 16 + nl;
    val[jn] = (n < POUT);
    jj[jn] = val[jn] ? n : 0;
#pragma unroll
    for (int kw = 0; kw < KW; ++kw) {
      int P = 2 * jj[jn] + kw - POFF + 4;
      rofs[jn][kw] = ((P & 1) * HRIN + (P >> 1)) * RS + q * 8;
    }
  }
  int aofs[MC];
#pragma unroll
  for (int i = 0; i < MC; ++i) {
    int r = (ct0 + i) * 16 + nl;
    aofs[i] = r * 32 + ((q + (r >> 2)) & 3) * 8;
  }

  f32x4 acc[MC][MN];
#pragma unroll
  for (int i = 0; i < MC; ++i)
#pragma unroll
    for (int jn = 0; jn < MN; ++jn) acc[i][jn] = (f32x4){0.f, 0.f, 0.f, 0.f};

  // prologue: issue chunks 0 and 1
  stage_chunk(wp, 0, 0, wbuf, tid);
  stage_chunk(wp, 0, 1, wbuf + 4096, tid);

#pragma unroll
  for (int s = 0; s < NS; ++s) {
    if (s < NS - 1) wait_vm_lgkm<1>(); else wait_vm_lgkm<0>();
    bar();
    if (s + 2 < NS)
      stage_chunk(wp, (s + 2) >> 2, (s + 2) & 3, wbuf + ((s + 2) % 3) * 4096, tid);
    const unsigned short* cb = wbuf + (s % 3) * 4096;
    const int kw = s >> 2, ks = s & 3;
    f16x8 a[MC], b[MN];
#pragma unroll
    for (int i = 0; i < MC; ++i) a[i] = *(const f16x8*)(cb + aofs[i]);
#pragma unroll
    for (int jn = 0; jn < MN; ++jn) b[jn] = *(const f16x8*)(sin_ + rofs[jn][kw] + ks * 32);
#pragma unroll
    for (int i = 0; i < MC; ++i)
#pragma unroll
      for (int jn = 0; jn < MN; ++jn)
        acc[i][jn] = __builtin_amdgcn_mfma_f32_16x16x32_f16(a[i], b[jn], acc[i][jn], 0, 0, 0);
  }

  // epilogue: C tile: col n = nl, rows cout = ct*16 + q*4 + r
#pragma unroll
  for (int i = 0; i < MC; ++i) {
#pragma unroll
    for (int jn = 0; jn < MN; ++jn) {
      if (!val[jn]) continue;
      unsigned int lo = (unsigned)f2h(lrelu(acc[i][jn][0])) | ((unsigned)f2h(lrelu(acc[i][jn][1])) << 16);
      unsigned int hi = (unsigned)f2h(lrelu(acc[i][jn][2])) | ((unsigned)f2h(lrelu(acc[i][jn][3])) << 16);
      const int j = jj[jn];
      if (OM == 1) {
        *(uint2*)(gact + ((size_t)frame * POUT + j) * 128 + (ct0 + i) * 16 + q * 4) = make_uint2(lo, hi);
      } else {
        const int row = (j & 1) * HROUT + (j >> 1) + 2;
        *(uint2*)(sout + (size_t)row * RS + (ct0 + i) * 16 + q * 4) = make_uint2(lo, hi);
      }
    }
  }
  if (OM == 0) {
    constexpr int DEND = ((POUT - 1) >> 1) + 3;
    constexpr int NZ = 2 + (HROUT - DEND);
    unsigned int* zp = (unsigned int*)sout;
    for (int s2 = tid; s2 < 2 * NZ * 68; s2 += 512) {
      int col = s2 % 68, rr = s2 / 68;
      int par = rr / NZ, rz = rr % NZ;
      int row = rz < 2 ? rz : DEND + rz - 2;
      zp[((size_t)par * HROUT + row) * 68 + col] = 0;
    }
  }
  // layer boundary: LDS writes visible to all waves; no DMA outstanding
  wait_lgkm0();
  bar();
}

// ---------------- E1: L0..L4, one block per frame (staged weights) ----------------
__global__ __launch_bounds__(512)
void encoder1(const float* __restrict__ x, const float* __restrict__ w0,
              const unsigned short* __restrict__ wp123,
              const unsigned short* __restrict__ wp4,
              unsigned short* __restrict__ act4g) {
  __shared__ __align__(16) unsigned short actA[18496];  // act0 (2*68 rows); later act2(2*20)+act3(2*12)
  __shared__ __align__(16) unsigned short actB[9792];   // act1 (2*36 rows); s_x overlaid pre-L1
  __shared__ __align__(16) unsigned short wbuf[12288];  // 3 x 8KB weight chunk buffers
  float* s_x = (float*)actB;                            // 262 floats, dead before L1 epilogue
  const int tid = threadIdx.x;
  const int frame = blockIdx.x;
  const int bb = frame >> 8;
  const int t = (frame & 255) + 256;

  if (tid < 256) s_x[3 + tid] = x[((bb << 8) + tid) * 512 + t];
  else if (tid < 259) s_x[tid - 256] = 0.f;
  else if (tid < 262) s_x[tid] = 0.f;
  wait_lgkm0();
  bar();

  // L0: 1->128, k7 s2 p3 (fp32 VALU), store fp16 parity layout
  {
    const int c = tid & 127;
    const int half = tid >> 7;
    float wv[7];
#pragma unroll
    for (int k = 0; k < 7; ++k) wv[k] = w0[c * 7 + k];
    for (int j = half * 32; j < half * 32 + 32; ++j) {
      float s = 0.f;
#pragma unroll
      for (int k = 0; k < 7; ++k) s += wv[k] * s_x[2 * j + k];
      int row = ((j & 1) ? 68 : 0) + (j >> 1) + 2;
      actA[row * RS + c] = f2h(lrelu(s));
    }
    unsigned int* zp = (unsigned int*)actA;
    for (int s2 = tid; s2 < 2 * 4 * 68; s2 += 512) {
      int col = s2 % 68;
      int rr = s2 / 68;
      int par = rr >> 2, r2 = rr & 3;
      int row = (r2 < 2) ? r2 : (64 + r2);
      zp[((size_t)par * 68 + row) * 68 + col] = 0;
    }
  }
  wait_lgkm0();
  bar();

  mlayer_s<7, 3, 128, 64, 2, 2, 0>(wp123,          actA, actB, nullptr, wbuf, tid, frame);        // L1
  mlayer_s<7, 3, 64, 32, 2, 1, 0>(wp123 + 114688,  actB, actA, nullptr, wbuf, tid, frame);        // L2
  mlayer_s<7, 3, 32, 16, 1, 1, 0>(wp123 + 229376,  actA, actA + 5440, nullptr, wbuf, tid, frame); // L3
  mlayer_s<3, 1, 16, 8, 1, 1, 1>(wp4,              actA + 5440, nullptr, act4g, wbuf, tid, frame);// L4 -> global
}

// ---------------- generic MFMA conv layer (encoder2) ----------------
template<int KW, int POFF, int PIN, int POUT, int FPB, int COUT, int MC, int MN, int OM, bool FLATIN>
__device__ __forceinline__ void mlayer(const unsigned short* __restrict__ wp,
                                       const unsigned short* __restrict__ sin_,
                                       unsigned short* __restrict__ sout,
                                       float* __restrict__ gout,
                                       int tid, int frame0) {
  constexpr int HRIN  = PIN / 2 + 4;
  constexpr int HROUT = POUT / 2 + 4;
  constexpr int NVAL = POUT * FPB;
  constexpr int Nt = (NVAL + 15) / 16;
  constexpr int Ct = COUT / 16;
  constexpr int MCg = Ct / MC, MNg = Nt / MN;
  constexpr int KS = 4;            // CIN=128 / 32
  constexpr int NS = KW * KS;
  constexpr int DA = NS < 6 ? NS : 6;
  constexpr int DB = NS < 3 ? NS : 3;
  constexpr int L2P = POUT == 1 ? 0 : POUT == 2 ? 1 : POUT == 4 ? 2 : POUT == 8 ? 3 :
                      POUT == 16 ? 4 : POUT == 32 ? 5 : 6;

  const int wid = tid >> 6, lane = tid & 63, nl = lane & 15, q = lane >> 4;

  for (int mac = wid; mac < MCg * MNg; mac += 8) {
    const int mcg = mac / MNg, mng = mac % MNg;
    const int ct0 = mcg * MC, nt0 = mng * MN;
    int jj[MN]; bool val[MN];
#pragma unroll
    for (int jn = 0; jn < MN; ++jn) {
      int n = (nt0 + jn) * 16 + nl;
      val[jn] = (n < NVAL);
      jj[jn] = val[jn] ? n : 0;
    }
    int rofs[MN][KW];
#pragma unroll
    for (int jn = 0; jn < MN; ++jn) {
      const int f = jj[jn] >> L2P, j = jj[jn] & (POUT - 1);
#pragma unroll
      for (int kw = 0; kw < KW; ++kw) {
        if (FLATIN) {
          rofs[jn][kw] = jj[jn] * RS + q * 8;
        } else {
          int P = 2 * j + kw - POFF + 4;
          rofs[jn][kw] = (f * 2 * HRIN + (P & 1) * HRIN + (P >> 1)) * RS + q * 8;
        }
      }
    }
    int abase[MC];
#pragma unroll
    for (int i = 0; i < MC; ++i) abase[i] = ((ct0 + i) * 16 + nl) * 128 + q * 8;

    f32x4 acc[MC][MN];
#pragma unroll
    for (int i = 0; i < MC; ++i)
#pragma unroll
      for (int jn = 0; jn < MN; ++jn) acc[i][jn] = (f32x4){0.f, 0.f, 0.f, 0.f};

    f16x8 A[DA][MC], B[DB][MN];
#pragma unroll
    for (int s = 0; s < DA; ++s) {
      const int kw = s / KS, ks = s % KS;
#pragma unroll
      for (int i = 0; i < MC; ++i)
        A[s][i] = *(const f16x8*)(wp + (size_t)kw * COUT * 128 + abase[i] + ks * 32);
    }
#pragma unroll
    for (int s = 0; s < DB; ++s) {
      const int kw = s / KS, ks = s % KS;
#pragma unroll
      for (int jn = 0; jn < MN; ++jn)
        B[s][jn] = *(const f16x8*)(sin_ + rofs[jn][kw] + ks * 32);
    }
#pragma unroll
    for (int s = 0; s < NS; ++s) {
      const int sa = s % DA, sb = s % DB;
#pragma unroll
      for (int i = 0; i < MC; ++i)
#pragma unroll
        for (int jn = 0; jn < MN; ++jn)
          acc[i][jn] = __builtin_amdgcn_mfma_f32_16x16x32_f16(A[sa][i], B[sb][jn], acc[i][jn], 0, 0, 0);
      if (s + DA < NS) {
        const int kw = (s + DA) / KS, ks = (s + DA) % KS;
#pragma unroll
        for (int i = 0; i < MC; ++i)
          A[sa][i] = *(const f16x8*)(wp + (size_t)kw * COUT * 128 + abase[i] + ks * 32);
      }
      if (s + DB < NS) {
        const int kw = (s + DB) / KS, ks = (s + DB) % KS;
#pragma unroll
        for (int jn = 0; jn < MN; ++jn)
          B[sb][jn] = *(const f16x8*)(sin_ + rofs[jn][kw] + ks * 32);
      }
    }
#pragma unroll
    for (int i = 0; i < MC; ++i) {
#pragma unroll
      for (int jn = 0; jn < MN; ++jn) {
        if (OM == 3) {
          if (val[jn]) {
            const int frame = frame0 + jj[jn];   // POUT==1
            float4 v = make_float4(acc[i][jn][0], acc[i][jn][1], acc[i][jn][2], acc[i][jn][3]);
            *(float4*)(gout + (size_t)frame * 256 + (ct0 + i) * 16 + q * 4) = v;
          }
        } else if (OM == 2) {
          if (val[jn]) {
            unsigned int lo = (unsigned)f2h(lrelu(acc[i][jn][0])) | ((unsigned)f2h(lrelu(acc[i][jn][1])) << 16);
            unsigned int hi = (unsigned)f2h(lrelu(acc[i][jn][2])) | ((unsigned)f2h(lrelu(acc[i][jn][3])) << 16);
            *(uint2*)(sout + (size_t)jj[jn] * RS + (ct0 + i) * 16 + q * 4) = make_uint2(lo, hi);
          }
        } else {
          if (val[jn]) {
            const int f = jj[jn] >> L2P, j = jj[jn] & (POUT - 1);
            const int row = f * 2 * HROUT + (j & 1) * HROUT + (j >> 1) + 2;
            unsigned int lo = (unsigned)f2h(lrelu(acc[i][jn][0])) | ((unsigned)f2h(lrelu(acc[i][jn][1])) << 16);
            unsigned int hi = (unsigned)f2h(lrelu(acc[i][jn][2])) | ((unsigned)f2h(lrelu(acc[i][jn][3])) << 16);
            *(uint2*)(sout + (size_t)row * RS + (ct0 + i) * 16 + q * 4) = make_uint2(lo, hi);
          }
        }
      }
    }
  }
  if (OM == 0) {
    constexpr int DEND = ((POUT - 1) >> 1) + 3;
    constexpr int NZ = 2 + (HROUT - DEND);
    constexpr int TOTU = FPB * 2 * NZ * (RS / 2);
    unsigned int* zp = (unsigned int*)sout;
    for (int s2 = tid; s2 < TOTU; s2 += 512) {
      int col = s2 % 68;
      int rr = s2 / 68;
      int fr = rr / (2 * NZ), r2 = rr % (2 * NZ);
      int par = r2 / NZ, rz = r2 % NZ;
      int row = rz < 2 ? rz : DEND + rz - 2;
      zp[((size_t)(fr * 2 + par) * HROUT + row) * 68 + col] = 0;
    }
    __syncthreads();
  } else if (OM == 2) {
    __syncthreads();
  }
}

// ---------------- E2: L5..L8, 8 frames per block ----------------
__global__ __launch_bounds__(512)
void encoder2(const unsigned short* __restrict__ act4g,
              const unsigned short* __restrict__ wp4,
              const unsigned short* __restrict__ wp8,
              float* __restrict__ h) {
  __shared__ __align__(16) unsigned short actP[17408];
  __shared__ __align__(16) unsigned short actQ[13056];
  __shared__ __align__(16) unsigned short actR[2176];
  const int tid = threadIdx.x;
  const int frame0 = blockIdx.x * 8;

  {
    uint4 z4 = make_uint4(0, 0, 0, 0);
    for (int s = tid; s < 2176; s += 512) ((uint4*)actP)[s] = z4;
    for (int s = tid; s < 1632; s += 512) ((uint4*)actQ)[s] = z4;
    for (int s = tid; s < 272; s += 512) ((uint4*)actR)[s] = z4;
  }
  __syncthreads();
  for (int c = tid; c < 1024; c += 512) {
    int f = c >> 7, rem = c & 127, pos = rem >> 4, o = (rem & 15) * 8;
    uint4 v = *(const uint4*)(act4g + ((size_t)(frame0 + f) * 8 + pos) * 128 + o);
    int P = pos + 4;
    int row = (P & 1) * 8 + (P >> 1);
    *(uint4*)(actP + ((size_t)f * 16 + row) * RS + o) = v;
  }
  __syncthreads();

  mlayer<3, 1, 8, 4, 8, 128, 2, 1, 0, false>(wp4 + 49152,  actP, actQ, nullptr, tid, frame0);  // L5
  mlayer<3, 1, 4, 2, 8, 128, 1, 1, 0, false>(wp4 + 98304,  actQ, actP, nullptr, tid, frame0);  // L6
  mlayer<3, 1, 2, 1, 8, 128, 1, 1, 2, false>(wp4 + 147456, actP, actR, nullptr, tid, frame0);  // L7 flat
  mlayer<1, 0, 1, 1, 8, 256, 1, 1, 3, true>(wp8,           actR, nullptr, h, tid, frame0);     // L8 -> h fp32
}

// ---------------- WaveNet fused layer (li 0..1) ----------------
__global__ __launch_bounds__(256)
void wnet_kernel(const unsigned short* __restrict__ wn,
                 const float* __restrict__ hsrc, float* __restrict__ hdst,
                 float* __restrict__ feats, int li, int init) {
  const int npos = 128 >> li, p = 1 << li, N = npos * 8, lnp = 7 - li;
  const int tid = threadIdx.x;
  const int nb = blockIdx.x >> 2, mb = blockIdx.x & 3;
  const int n0 = nb * 16;
  __shared__ __align__(16) unsigned short sB[16 * 520];

  for (int c = tid; c < 1024; c += 256) {
    const int nr = c >> 6, o = (c & 63) * 8;
    const int n = n0 + nr;
    unsigned short tmp[8] = {0, 0, 0, 0, 0, 0, 0, 0};
    if (n < N) {
      const int b = n >> lnp, kk = n & (npos - 1);
      const int t = 255 - (kk << (li + 1));
      const float* src = (o < 256) ? hsrc + ((size_t)(b * 256 + t - p)) * 256 + o
                                   : hsrc + ((size_t)(b * 256 + t)) * 256 + (o - 256);
#pragma unroll
      for (int e = 0; e < 8; ++e) tmp[e] = f2h(src[e]);
    }
    unsigned int u0 = (unsigned)tmp[0] | ((unsigned)tmp[1] << 16);
    unsigned int u1 = (unsigned)tmp[2] | ((unsigned)tmp[3] << 16);
    unsigned int u2 = (unsigned)tmp[4] | ((unsigned)tmp[5] << 16);
    unsigned int u3 = (unsigned)tmp[6] | ((unsigned)tmp[7] << 16);
    *(uint4*)(sB + (size_t)nr * 520 + o) = make_uint4(u0, u1, u2, u3);
  }
  __syncthreads();

  const int wid = tid >> 6, lane = tid & 63, nl = lane & 15, q = lane >> 4;
  f32x4 acc[2];
  acc[0] = (f32x4){0.f, 0.f, 0.f, 0.f};
  acc[1] = (f32x4){0.f, 0.f, 0.f, 0.f};
  int arow[2];
#pragma unroll
  for (int i = 0; i < 2; ++i) arow[i] = (mb * 128 + (wid * 2 + i) * 16 + nl) * 512 + q * 8;
  const int bofs = nl * 520 + q * 8;

  f16x8 A[4][2], Bv[2];
#pragma unroll
  for (int s = 0; s < 4; ++s)
#pragma unroll
    for (int i = 0; i < 2; ++i) A[s][i] = *(const f16x8*)(wn + arow[i] + s * 32);
#pragma unroll
  for (int s = 0; s < 2; ++s) Bv[s] = *(const f16x8*)(sB + bofs + s * 32);
#pragma unroll
  for (int s = 0; s < 16; ++s) {
    const int sa = s & 3, sb = s & 1;
    acc[0] = __builtin_amdgcn_mfma_f32_16x16x32_f16(A[sa][0], Bv[sb], acc[0], 0, 0, 0);
    acc[1] = __builtin_amdgcn_mfma_f32_16x16x32_f16(A[sa][1], Bv[sb], acc[1], 0, 0, 0);
    if (s + 4 < 16) {
#pragma unroll
      for (int i = 0; i < 2; ++i) A[sa][i] = *(const f16x8*)(wn + arow[i] + (s + 4) * 32);
    }
    if (s + 2 < 16) Bv[sb] = *(const f16x8*)(sB + bofs + (s + 2) * 32);
  }

  const int n = n0 + nl;
  if (n < N) {
    const int b = n >> lnp, kk = n & (npos - 1);
    const int t = 255 - (kk << (li + 1));
    const size_t rowoff = ((size_t)(b * 256 + t)) * 256;
#pragma unroll
    for (int i = 0; i < 2; ++i) {
      const int ch = mb * 64 + (wid * 2 + i) * 8 + q * 2;
      const float z0 = tanhf(acc[i][0]) * (1.f / (1.f + expf(-acc[i][1])));
      const float z1 = tanhf(acc[i][2]) * (1.f / (1.f + expf(-acc[i][3])));
      float2 hv = *(const float2*)(hsrc + rowoff + ch);
      *(float2*)(hdst + rowoff + ch) = make_float2(hv.x + z0, hv.y + z1);
      if (kk == 0) {
        float* fp = feats + b * 256 + ch;
        if (init) { fp[0] = z0; fp[1] = z1; }
        else { fp[0] += z0; fp[1] += z1; }
      }
    }
  }
}

// ---------------- WaveNet K-split stage A (li 2..7) ----------------
template<int KC>
__global__ __launch_bounds__(256)
void wnet_partA(const unsigned short* __restrict__ wn,
                const float* __restrict__ hsrc,
                float* __restrict__ pb, int li) {
  const int npos = 128 >> li, p = 1 << li, N = npos * 8, lnp = 7 - li;
  const int NN = (N + 15) / 16;
  const int tid = threadIdx.x;
  int bid = blockIdx.x;
  const int mb = bid & 3; bid >>= 2;
  const int nb = bid % NN; const int ks = bid / NN;
  const int n0 = nb * 16;
  const int kc0 = ks * KC;
  constexpr int RSB = KC + 8;
  __shared__ __align__(16) unsigned short sB[16 * RSB];

  for (int c = tid; c < 2 * KC; c += 256) {
    const int nr = c / (KC / 8), oc = c % (KC / 8), o = oc * 8;
    const int kg = kc0 + o;
    const int n = n0 + nr;
    unsigned short tmp[8] = {0, 0, 0, 0, 0, 0, 0, 0};
    if (n < N) {
      const int b = n >> lnp, kk = n & (npos - 1);
      const int t = 255 - (kk << (li + 1));
      const float* src = (kg < 256) ? hsrc + ((size_t)(b * 256 + t - p)) * 256 + kg
                                    : hsrc + ((size_t)(b * 256 + t)) * 256 + (kg - 256);
#pragma unroll
      for (int e = 0; e < 8; ++e) tmp[e] = f2h(src[e]);
    }
    unsigned int u0 = (unsigned)tmp[0] | ((unsigned)tmp[1] << 16);
    unsigned int u1 = (unsigned)tmp[2] | ((unsigned)tmp[3] << 16);
    unsigned int u2 = (unsigned)tmp[4] | ((unsigned)tmp[5] << 16);
    unsigned int u3 = (unsigned)tmp[6] | ((unsigned)tmp[7] << 16);
    *(uint4*)(sB + (size_t)nr * RSB + o) = make_uint4(u0, u1, u2, u3);
  }
  __syncthreads();

  const int wid = tid >> 6, lane = tid & 63, nl = lane & 15, q = lane >> 4;
  f32x4 acc[2];
  acc[0] = (f32x4){0.f, 0.f, 0.f, 0.f};
  acc[1] = (f32x4){0.f, 0.f, 0.f, 0.f};
  int arow[2];
#pragma unroll
  for (int i = 0; i < 2; ++i) arow[i] = (mb * 128 + (wid * 2 + i) * 16 + nl) * 512 + kc0 + q * 8;
  const int bofs = nl * RSB + q * 8;

  constexpr int NS = KC / 32;
  constexpr int DA = NS < 4 ? NS : 4;
  constexpr int DB = NS < 2 ? NS : 2;
  f16x8 A[DA][2], Bv[DB];
#pragma unroll
  for (int s = 0; s < DA; ++s)
#pragma unroll
    for (int i = 0; i < 2; ++i) A[s][i] = *(const f16x8*)(wn + arow[i] + s * 32);
#pragma unroll
  for (int s = 0; s < DB; ++s) Bv[s] = *(const f16x8*)(sB + bofs + s * 32);
#pragma unroll
  for (int s = 0; s < NS; ++s) {
    const int sa = s % DA, sb = s % DB;
    acc[0] = __builtin_amdgcn_mfma_f32_16x16x32_f16(A[sa][0], Bv[sb], acc[0], 0, 0, 0);
    acc[1] = __builtin_amdgcn_mfma_f32_16x16x32_f16(A[sa][1], Bv[sb], acc[1], 0, 0, 0);
    if (s + DA < NS) {
#pragma unroll
      for (int i = 0; i < 2; ++i) A[sa][i] = *(const f16x8*)(wn + arow[i] + (s + DA) * 32);
    }
    if (s + DB < NS) Bv[sb] = *(const f16x8*)(sB + bofs + (s + DB) * 32);
  }
  float* base = pb + ((size_t)((ks * NN + nb) * 4 + mb) * 256 + tid) * 8;
  *(f32x4*)(base) = acc[0];
  *(f32x4*)(base + 4) = acc[1];
}

// ---------------- WaveNet K-split stage B: combine + epilogue ----------------
__global__ __launch_bounds__(256)
void wnet_partB(const float* __restrict__ pb,
                const float* __restrict__ hsrc, float* __restrict__ hdst,
                float* __restrict__ feats, int li, int ksplit) {
  const int npos = 128 >> li, N = npos * 8, lnp = 7 - li;
  const int NN = (N + 15) / 16;
  const int nb = blockIdx.x >> 2, mb = blockIdx.x & 3;
  const int n0 = nb * 16;
  const int tid = threadIdx.x;
  const int wid = tid >> 6, lane = tid & 63, nl = lane & 15, q = lane >> 4;
  float acc[8] = {0, 0, 0, 0, 0, 0, 0, 0};
  for (int ks = 0; ks < ksplit; ++ks) {
    const float* base = pb + ((size_t)((ks * NN + nb) * 4 + mb) * 256 + tid) * 8;
    float4 v0 = *(const float4*)(base);
    float4 v1 = *(const float4*)(base + 4);
    acc[0] += v0.x; acc[1] += v0.y; acc[2] += v0.z; acc[3] += v0.w;
    acc[4] += v1.x; acc[5] += v1.y; acc[6] += v1.z; acc[7] += v1.w;
  }
  const int n = n0 + nl;
  if (n < N) {
    const int b = n >> lnp, kk = n & (npos - 1);
    const int t = 255 - (kk << (li + 1));
    const size_t rowoff = ((size_t)(b * 256 + t)) * 256;
#pragma unroll
    for (int i = 0; i < 2; ++i) {
      const int ch = mb * 64 + (wid * 2 + i) * 8 + q * 2;
      const float z0 = tanhf(acc[i * 4 + 0]) * (1.f / (1.f + expf(-acc[i * 4 + 1])));
      const float z1 = tanhf(acc[i * 4 + 2]) * (1.f / (1.f + expf(-acc[i * 4 + 3])));
      float2 hv = *(const float2*)(hsrc + rowoff + ch);
      *(float2*)(hdst + rowoff + ch) = make_float2(hv.x + z0, hv.y + z1);
      if (kk == 0) {
        float* fp = feats + b * 256 + ch;
        fp[0] += z0; fp[1] += z1;
      }
    }
  }
}

__global__ void finalize_kernel(const float* __restrict__ feats,
                                const float* __restrict__ jw,
                                float* __restrict__ out) {
  __shared__ float red[256];
  const int b = blockIdx.x;
  const int tid = threadIdx.x;
  const float v = feats[b * 256 + tid];
  out[b * 256 + tid] = v;
  red[tid] = v * jw[tid];
  __syncthreads();
  for (int s = 128; s > 0; s >>= 1) {
    if (tid < s) red[tid] += red[tid + s];
    __syncthreads();
  }
  if (tid == 0) out[NB * 256 + b] = red[0];
}

extern "C" void kernel_launch(void* const* d_in, const int* in_sizes, int n_in,
                              void* d_out, int out_size, void* d_ws, size_t ws_size,
                              hipStream_t stream) {
  const float* x     = (const float*)d_in[0];
  const float* w0    = (const float*)d_in[1];
  const float* w123  = (const float*)d_in[2];
  const float* w4567 = (const float*)d_in[3];
  const float* w8    = (const float*)d_in[4];
  const float* mw    = (const float*)d_in[5];
  const float* gw    = (const float*)d_in[6];
  const float* jw    = (const float*)d_in[7];
  float* out = (float*)d_out;

  float* ws = (float*)d_ws;
  unsigned short* act4g = (unsigned short*)ws;            // 2,097,152 fp16
  float* h0    = ws + 1048576;                            // 524,288 f
  float* h1    = ws + 1572864;                            // 524,288 f
  float* feats = ws + 2097152;                            // 2,048 f
  unsigned short* wp = (unsigned short*)(ws + 2099200);   // 573,440 fp16
  unsigned short* wn = (unsigned short*)(ws + 2385920);   // 2,097,152 fp16
  float* pb    = ws + 3434496;                            // 262,144 f

  pack_kernel<<<5216, 512, 0, stream>>>(w123, w4567, w8, mw, gw, wp, wn);
  encoder1<<<2048, 512, 0, stream>>>(x, w0, wp, wp + N1, act4g);
  encoder2<<<256, 512, 0, stream>>>(act4g, wp + N1, wp + N1 + N2, h0);

  float* hs = h0; float* hd = h1;
  for (int i = 0; i < 8; ++i) {
    const unsigned short* wl = wn + (size_t)i * 262144;
    const int N = (128 >> i) * 8;
    const int nN = (N + 15) / 16;
    if (i < 2) {
      wnet_kernel<<<4 * nN, 256, 0, stream>>>(wl, hs, hd, feats, i, i == 0 ? 1 : 0);
    } else {
      int ksplit;
      if (i == 2)      { ksplit = 2;  wnet_partA<256><<<4 * nN * 2,  256, 0, stream>>>(wl, hs, pb, i); }
      else if (i == 3) { ksplit = 4;  wnet_partA<128><<<4 * nN * 4,  256, 0, stream>>>(wl, hs, pb, i); }
      else if (i == 4) { ksplit = 8;  wnet_partA<64> <<<4 * nN * 8,  256, 0, stream>>>(wl, hs, pb, i); }
      else             { ksplit = 16; wnet_partA<32> <<<4 * nN * 16, 256, 0, stream>>>(wl, hs, pb, i); }
      wnet_partB<<<4 * nN, 256, 0, stream>>>(pb, hs, hd, feats, i, ksplit);
    }
    float* tmp = hd; hd = hs; hs = tmp;
  }
  finalize_kernel<<<NB, 256, 0, stream>>>(feats, jw, out);
}